// Round 1
// baseline (203.439 us; speedup 1.0000x reference)
//
#include <hip/hip_runtime.h>
#include <math.h>

#define N_PRED  12
#define N_DRIFT 2
#define N_DW    3
#define N_NODES 4096
#define BB      128
#define LL      16
#define BN      (BB * N_NODES)   // 524288 pairs

// ---------------------------------------------------------------------------
// Pre-kernel: fold (deform ∘ conv_t) and (deform ∘ conv_n) into dense uniform
// matrices Mt, Mn of shape [N_DW*LL][N_PRED] = [48][12] each.
//   pred_t[q] = sum_{k,l} Mt[(k*16+l)*12+q] * x[k][l]  (+ conv_t_b)
//   pred_n[q] = sum_{k,l} Mn[(k*16+l)*12+q] * x[k][l]  (+ conv_n_b[q])
// 576 threads, one block, ~free. Runs every launch (ws is re-poisoned).
// ---------------------------------------------------------------------------
__global__ void deform_precompute(const float* __restrict__ offset_t,
                                  const float* __restrict__ offset_n,
                                  const float* __restrict__ conv_t_w,
                                  const float* __restrict__ conv_n_w,
                                  float* __restrict__ Mt,
                                  float* __restrict__ Mn) {
    int t = threadIdx.x;
    if (t >= N_PRED * N_DW * LL) return;      // 576
    int q  = t % N_PRED;
    int kl = t / N_PRED;
    int k  = kl / LL;
    int l  = kl % LL;

    // deform coefficient for (k, column c, source l), table = offset pointer
    auto coef = [&](const float* off, int c) -> float {
        float pos = tanhf(off[k * N_PRED + c]) * (float)N_DRIFT
                    + (float)(c + N_DRIFT);
        float idf = floorf(pos);
        float fr  = pos - idf;
        int   id  = (int)idf;                 // in [c, c+3], id+1 <= 15
        if (l == id)     return 1.0f - fr;
        if (l == id + 1) return fr;
        return 0.0f;
    };

    // Mt: conv_t (O=1,I=3,H=3, pad 1) over deformed dt
    float mt = 0.0f;
    #pragma unroll
    for (int h = 0; h < 3; ++h) {
        int c = q - 1 + h;
        if (c < 0 || c >= N_PRED) continue;
        mt += conv_t_w[k * 3 + h] * coef(offset_t, c);
    }

    // Mn: einsum('bkc,ock->bo') over deformed dn ; conv_n_w shape (o,c,k)
    float mn = 0.0f;
    #pragma unroll
    for (int c = 0; c < N_PRED; ++c) {
        mn += conv_n_w[q * (N_PRED * N_DW) + c * N_DW + k] * coef(offset_n, c);
    }

    Mt[kl * N_PRED + q] = mt;
    Mn[kl * N_PRED + q] = mn;
}

// ---------------------------------------------------------------------------
// Main kernel: one thread per (b,n) pair.
//   x[48] in VGPRs (12 coalesced float4 loads), weights via wave-uniform
//   s_load (SGPR operands) -> no LDS anywhere, no dynamic indexing.
// ---------------------------------------------------------------------------
__global__ __launch_bounds__(256) void deform_main(
        const float* __restrict__ inp,      // (BN, 3, 16)
        const float* __restrict__ ctrl,     // (BN, 12)
        const float* __restrict__ W,        // (12, 12)
        const float* __restrict__ bparam,   // (N_NODES, 12)
        const float* __restrict__ conv_t_b, // (1,)
        const float* __restrict__ conv_n_b, // (12,)
        const float* __restrict__ Mt,       // (48, 12)
        const float* __restrict__ Mn,       // (48, 12)
        float* __restrict__ out) {          // (BN, 12)
    int tid = blockIdx.x * 256 + threadIdx.x;   // < BN exactly
    int n   = tid & (N_NODES - 1);

    // ---- load x: 48 contiguous floats -> registers ----
    float x[48];
    const float4* xp = (const float4*)(inp + (size_t)tid * 48);
    #pragma unroll
    for (int i = 0; i < 12; ++i) {
        float4 v = xp[i];
        x[4 * i + 0] = v.x; x[4 * i + 1] = v.y;
        x[4 * i + 2] = v.z; x[4 * i + 3] = v.w;
    }

    // ---- load ctrl row (12 floats) ----
    float c[12];
    const float4* cp = (const float4*)(ctrl + (size_t)tid * N_PRED);
    #pragma unroll
    for (int i = 0; i < 3; ++i) {
        float4 v = cp[i];
        c[4 * i + 0] = v.x; c[4 * i + 1] = v.y;
        c[4 * i + 2] = v.z; c[4 * i + 3] = v.w;
    }

    // ---- gate accumulator starts at bparam[n] ----
    float accg[12];
    const float4* bp = (const float4*)(bparam + (size_t)n * N_PRED);
    #pragma unroll
    for (int i = 0; i < 3; ++i) {
        float4 v = bp[i];
        accg[4 * i + 0] = v.x; accg[4 * i + 1] = v.y;
        accg[4 * i + 2] = v.z; accg[4 * i + 3] = v.w;
    }

    // ---- pred_t / pred_n accumulators (biases) ----
    float acct[12], accn[12];
    float ctb = conv_t_b[0];
    #pragma unroll
    for (int q = 0; q < N_PRED; ++q) {
        acct[q] = ctb;
        accn[q] = conv_n_b[q];
    }

    // ---- the two folded matvecs: 1152 FMAs, weights s_load-uniform ----
    #pragma unroll
    for (int kl = 0; kl < 48; ++kl) {
        float xv = x[kl];
        #pragma unroll
        for (int q = 0; q < N_PRED; ++q) {
            acct[q] = fmaf(Mt[kl * N_PRED + q], xv, acct[q]);
            accn[q] = fmaf(Mn[kl * N_PRED + q], xv, accn[q]);
        }
    }

    // ---- gate matvec: ctrl . W  (+bparam already in accg) ----
    #pragma unroll
    for (int p = 0; p < N_PRED; ++p) {
        float cv = c[p];
        #pragma unroll
        for (int q = 0; q < N_PRED; ++q) {
            accg[q] = fmaf(cv, W[p * N_PRED + q], accg[q]);
        }
    }

    // ---- sigmoid gate + blend, vectorized store ----
    float4 o4[3];
    float* ov = (float*)o4;
    #pragma unroll
    for (int q = 0; q < N_PRED; ++q) {
        float g = 1.0f / (1.0f + __expf(-accg[q]));
        ov[q] = accn[q] * g + acct[q] * (1.0f - g);
    }
    float4* op = (float4*)(out + (size_t)tid * N_PRED);
    op[0] = o4[0]; op[1] = o4[1]; op[2] = o4[2];
}

extern "C" void kernel_launch(void* const* d_in, const int* in_sizes, int n_in,
                              void* d_out, int out_size, void* d_ws, size_t ws_size,
                              hipStream_t stream) {
    const float* inp      = (const float*)d_in[0];
    const float* ctrl     = (const float*)d_in[1];
    const float* offset_t = (const float*)d_in[2];
    const float* offset_n = (const float*)d_in[3];
    const float* conv_t_w = (const float*)d_in[4];
    const float* conv_t_b = (const float*)d_in[5];
    const float* conv_n_w = (const float*)d_in[6];
    const float* conv_n_b = (const float*)d_in[7];
    const float* W        = (const float*)d_in[8];
    const float* bparam   = (const float*)d_in[9];
    float* out = (float*)d_out;

    float* Mt = (float*)d_ws;            // 576 floats
    float* Mn = Mt + N_DW * LL * N_PRED; // 576 floats  (ws needs >= 4608 B)

    deform_precompute<<<1, 576, 0, stream>>>(offset_t, offset_n,
                                             conv_t_w, conv_n_w, Mt, Mn);
    deform_main<<<BN / 256, 256, 0, stream>>>(inp, ctrl, W, bparam,
                                              conv_t_b, conv_n_b, Mt, Mn, out);
}

// Round 2
// 202.692 us; speedup vs baseline: 1.0037x; 1.0037x over previous
//
#include <hip/hip_runtime.h>
#include <math.h>

#define N_PRED  12
#define N_DRIFT 2
#define N_DW    3
#define N_NODES 4096
#define BB      128
#define LL      16
#define BN      (BB * N_NODES)   // 524288 pairs
#define TPB     128              // threads (= pairs) per block
#define NBLK    (BN / TPB)       // 4096 blocks
#define XROW    13               // float4 slots per pair row (12 data + 1 pad)

// ---------------------------------------------------------------------------
// Pre-kernel: fold (deform ∘ conv_t) and (deform ∘ conv_n) into dense uniform
// matrices Mt, Mn of shape [48][12]. Unchanged from R1 (verified correct).
// ---------------------------------------------------------------------------
__global__ void deform_precompute(const float* __restrict__ offset_t,
                                  const float* __restrict__ offset_n,
                                  const float* __restrict__ conv_t_w,
                                  const float* __restrict__ conv_n_w,
                                  float* __restrict__ Mt,
                                  float* __restrict__ Mn) {
    int t = threadIdx.x;
    if (t >= N_PRED * N_DW * LL) return;      // 576
    int q  = t % N_PRED;
    int kl = t / N_PRED;
    int k  = kl / LL;
    int l  = kl % LL;

    auto coef = [&](const float* off, int c) -> float {
        float pos = tanhf(off[k * N_PRED + c]) * (float)N_DRIFT
                    + (float)(c + N_DRIFT);
        float idf = floorf(pos);
        float fr  = pos - idf;
        int   id  = (int)idf;
        if (l == id)     return 1.0f - fr;
        if (l == id + 1) return fr;
        return 0.0f;
    };

    float mt = 0.0f;
    #pragma unroll
    for (int h = 0; h < 3; ++h) {
        int c = q - 1 + h;
        if (c < 0 || c >= N_PRED) continue;
        mt += conv_t_w[k * 3 + h] * coef(offset_t, c);
    }

    float mn = 0.0f;
    #pragma unroll
    for (int c = 0; c < N_PRED; ++c) {
        mn += conv_n_w[q * (N_PRED * N_DW) + c * N_DW + k] * coef(offset_n, c);
    }

    Mt[kl * N_PRED + q] = mt;
    Mn[kl * N_PRED + q] = mn;
}

// ---------------------------------------------------------------------------
// Main kernel, R2: LDS-staged coalesced loads.
//  - global->reg->LDS staging: every global_load_dwordx4 is lane-contiguous
//    (1 KB/wave/instr) instead of 192-B-strided (64 lines/instr in R1).
//  - x rows stored at stride 13 float4: b128 read quad-bank = (13t+c)%8,
//    13 coprime 8 -> conflict-free. ctrl natural stride 3 float4: (3t+i)%8 ok.
//  - outputs restaged through LDS so stores are also lane-contiguous.
//  - LDS = 32768 B exactly -> 5 blocks/CU (10 waves/CU).
// ---------------------------------------------------------------------------
__global__ __launch_bounds__(TPB) void deform_main(
        const float* __restrict__ inp,      // (BN, 3, 16)
        const float* __restrict__ ctrl,     // (BN, 12)
        const float* __restrict__ W,        // (12, 12)
        const float* __restrict__ bparam,   // (N_NODES, 12)
        const float* __restrict__ conv_t_b, // (1,)
        const float* __restrict__ conv_n_b, // (12,)
        const float* __restrict__ Mt,       // (48, 12)
        const float* __restrict__ Mn,       // (48, 12)
        float* __restrict__ out) {          // (BN, 12)
    __shared__ float4 xs4[TPB * XROW];      // 26624 B
    __shared__ float4 cs4[TPB * 3];         //  6144 B  (total 32 KB exact)

    const int t   = threadIdx.x;
    const int tid = blockIdx.x * TPB + t;
    const int n   = tid & (N_NODES - 1);

    // ---- stage x: 12 fully-coalesced float4 loads -> swizzled LDS rows ----
    const float4* gin = (const float4*)inp + (size_t)blockIdx.x * (TPB * 12);
    #pragma unroll
    for (int i = 0; i < 12; ++i) {
        int A = i * TPB + t;                // chunk index within block
        float4 v = gin[A];
        xs4[(A / 12) * XROW + (A % 12)] = v;
    }
    // ---- stage ctrl: natural layout (stride 3 float4 is conflict-free) ----
    const float4* gct = (const float4*)ctrl + (size_t)blockIdx.x * (TPB * 3);
    #pragma unroll
    for (int i = 0; i < 3; ++i) {
        int A = i * TPB + t;
        cs4[A] = gct[A];
    }
    __syncthreads();

    // ---- LDS -> registers: conflict-free b128 reads ----
    float x[48];
    #pragma unroll
    for (int c = 0; c < 12; ++c) {
        float4 v = xs4[t * XROW + c];
        x[4 * c + 0] = v.x; x[4 * c + 1] = v.y;
        x[4 * c + 2] = v.z; x[4 * c + 3] = v.w;
    }
    float cr[12];
    #pragma unroll
    for (int i = 0; i < 3; ++i) {
        float4 v = cs4[t * 3 + i];
        cr[4 * i + 0] = v.x; cr[4 * i + 1] = v.y;
        cr[4 * i + 2] = v.z; cr[4 * i + 3] = v.w;
    }

    // ---- gate accumulator starts at bparam[n] (L2-resident, 192 KB) ----
    float accg[12];
    {
        const float* bp = bparam + (size_t)n * N_PRED;
        #pragma unroll
        for (int i = 0; i < 3; ++i) {
            float4 v = *(const float4*)(bp + 4 * i);
            accg[4 * i + 0] = v.x; accg[4 * i + 1] = v.y;
            accg[4 * i + 2] = v.z; accg[4 * i + 3] = v.w;
        }
    }

    // ---- pred_t / pred_n accumulators (biases) ----
    float acct[12], accn[12];
    float ctb = conv_t_b[0];
    #pragma unroll
    for (int q = 0; q < N_PRED; ++q) {
        acct[q] = ctb;
        accn[q] = conv_n_b[q];
    }

    // ---- folded matvecs: 1152 FMAs, weights wave-uniform (s_load) ----
    #pragma unroll
    for (int kl = 0; kl < 48; ++kl) {
        float xv = x[kl];
        #pragma unroll
        for (int q = 0; q < N_PRED; ++q) {
            acct[q] = fmaf(Mt[kl * N_PRED + q], xv, acct[q]);
            accn[q] = fmaf(Mn[kl * N_PRED + q], xv, accn[q]);
        }
    }

    // ---- gate matvec ----
    #pragma unroll
    for (int p = 0; p < N_PRED; ++p) {
        float cv = cr[p];
        #pragma unroll
        for (int q = 0; q < N_PRED; ++q) {
            accg[q] = fmaf(cv, W[p * N_PRED + q], accg[q]);
        }
    }

    // ---- sigmoid gate + blend ----
    float4 o4[3];
    float* ov = (float*)o4;
    #pragma unroll
    for (int q = 0; q < N_PRED; ++q) {
        float g = 1.0f / (1.0f + __expf(-accg[q]));
        ov[q] = accn[q] * g + acct[q] * (1.0f - g);
    }

    // ---- restage outputs through LDS for coalesced stores ----
    __syncthreads();                         // xs4 reads all done
    #pragma unroll
    for (int j = 0; j < 3; ++j) {
        xs4[t * 3 + j] = o4[j];              // quad (3t+j)%8: conflict-free
    }
    __syncthreads();
    float4* gout = (float4*)out + (size_t)blockIdx.x * (TPB * 3);
    #pragma unroll
    for (int j = 0; j < 3; ++j) {
        int A = j * TPB + t;
        gout[A] = xs4[A];                    // lane-contiguous 1 KB stores
    }
}

extern "C" void kernel_launch(void* const* d_in, const int* in_sizes, int n_in,
                              void* d_out, int out_size, void* d_ws, size_t ws_size,
                              hipStream_t stream) {
    const float* inp      = (const float*)d_in[0];
    const float* ctrl     = (const float*)d_in[1];
    const float* offset_t = (const float*)d_in[2];
    const float* offset_n = (const float*)d_in[3];
    const float* conv_t_w = (const float*)d_in[4];
    const float* conv_t_b = (const float*)d_in[5];
    const float* conv_n_w = (const float*)d_in[6];
    const float* conv_n_b = (const float*)d_in[7];
    const float* W        = (const float*)d_in[8];
    const float* bparam   = (const float*)d_in[9];
    float* out = (float*)d_out;

    float* Mt = (float*)d_ws;            // 576 floats
    float* Mn = Mt + N_DW * LL * N_PRED; // 576 floats (ws >= 4608 B)

    deform_precompute<<<1, 576, 0, stream>>>(offset_t, offset_n,
                                             conv_t_w, conv_n_w, Mt, Mn);
    deform_main<<<NBLK, TPB, 0, stream>>>(inp, ctrl, W, bparam,
                                          conv_t_b, conv_n_b, Mt, Mn, out);
}